// Round 10
// baseline (708.921 us; speedup 1.0000x reference)
//
#include <hip/hip_runtime.h>
#include <hip/hip_bf16.h>
#include <hip/hip_cooperative_groups.h>

namespace cg = cooperative_groups;

#define DIM 64
#define NREL 8
#define KTOT 576            // Wt2 rows: 512 rel-cols + 64 root cols

typedef __bf16 bf16x8 __attribute__((ext_vector_type(8)));
typedef __bf16 bf16x4 __attribute__((ext_vector_type(4)));
typedef float  f32x4  __attribute__((ext_vector_type(4)));

// ---------------- fused: hist (rank-returning) + initial gather + sentinels ----------------
__global__ __launch_bounds__(256) void histgather_kernel(const int* __restrict__ dst,
                                                         const int* __restrict__ et,
                                                         int* __restrict__ deg8,
                                                         int* __restrict__ eoff,
                                                         const int* __restrict__ x_idx,
                                                         const float* __restrict__ emb,
                                                         __bf16* __restrict__ xb0,
                                                         __bf16* __restrict__ hbuf,
                                                         int* __restrict__ srcs,
                                                         int N, int E, int epad_cap) {
    int i = blockIdx.x * 256 + threadIdx.x;
    if (i < N * DIM) {
        int n = i >> 6;
        int c = i & 63;
        xb0[i] = (__bf16)emb[(size_t)x_idx[n] * DIM + c];
    }
    if (i < DIM) {                                        // sentinel zero row in h (gidx = 8N)
        hbuf[(size_t)N * NREL * DIM + i] = (__bf16)0.f;
    }
    if (i < epad_cap) srcs[i] = N * NREL;                 // padding -> sentinel gidx
    if (i < E) eoff[i] = atomicAdd(&deg8[dst[i] * 8 + et[i]], 1);  // rank within (dst,rel) cell
}

// ---------------- scan1 over per-dst ROW-PADDED totals + invdeg (true deg) ----------------
__global__ __launch_bounds__(256) void scan1_kernel(const int* __restrict__ deg8,
                                                    int* __restrict__ offs,
                                                    int* __restrict__ bsum,
                                                    float* __restrict__ invdeg, int N) {
    __shared__ int sd[256];
    int tid = threadIdx.x;
    int d = blockIdx.x * 256 + tid;
    int vpad = 0;
    if (d < N) {
        int vtrue = 0;
#pragma unroll
        for (int r = 0; r < NREL; ++r) vtrue += deg8[d * 8 + r];
        vpad = (vtrue + 3) & ~3;                          // pad per ROW
        invdeg[d] = 1.0f / fmaxf((float)vtrue, 1.0f);
    }
    sd[tid] = vpad;
    __syncthreads();
#pragma unroll
    for (int off = 1; off < 256; off <<= 1) {
        int t = (tid >= off) ? sd[tid - off] : 0;
        __syncthreads();
        sd[tid] += t;
        __syncthreads();
    }
    if (d < N) offs[d] = sd[tid] - vpad;
    if (tid == 255) bsum[blockIdx.x] = sd[255];
}

// ---------------- scan2 (block 0) + wcat (blocks >= 1) fused ----------------
// Wt2[l][row][ch]: row<512 -> row=r*64+c maps weight[l][r][ch][c]; row>=512 -> root[l][ch][row-512]
__global__ __launch_bounds__(512) void scan2wcat_kernel(int* __restrict__ bsum, int nb,
                                                        const float* __restrict__ weight,
                                                        const float* __restrict__ root,
                                                        __bf16* __restrict__ Wt2, int L) {
    if (blockIdx.x == 0) {
        __shared__ int sd[512];
        int tid = threadIdx.x;
        int v = (tid < nb) ? bsum[tid] : 0;
        sd[tid] = v;
        __syncthreads();
#pragma unroll
        for (int off = 1; off < 512; off <<= 1) {
            int t = (tid >= off) ? sd[tid - off] : 0;
            __syncthreads();
            sd[tid] += t;
            __syncthreads();
        }
        if (tid < nb) bsum[tid] = sd[tid] - v;
    } else {
        int idx = (blockIdx.x - 1) * 512 + threadIdx.x;
        int total = L * KTOT * DIM;
        if (idx >= total) return;
        int l = idx / (KTOT * DIM);
        int rem = idx - l * (KTOT * DIM);
        int row = rem / DIM;
        int ch = rem - row * DIM;
        float w;
        if (row < 512) {
            int r = row >> 6, c = row & 63;
            w = weight[(((l * 8 + r) * 64) + ch) * 64 + c];
        } else {
            w = root[(l * 64 + ch) * 64 + (row - 512)];
        }
        Wt2[idx] = (__bf16)w;
    }
}

// ---------------- rp build: exact cell starts within row-padded slot space ----------------
__global__ __launch_bounds__(256) void rpbuild_kernel(const int* __restrict__ deg8,
                                                      const int* __restrict__ offs,
                                                      const int* __restrict__ bsum,
                                                      int* __restrict__ rp,
                                                      int N) {
    int d = blockIdx.x * 256 + threadIdx.x;
    if (d >= N) return;
    int base = offs[d] + bsum[blockIdx.x];
    int run = 0;
#pragma unroll
    for (int r = 0; r < NREL; ++r) {
        rp[d * 8 + r] = base + run;
        run += deg8[d * 8 + r];                           // exact (no per-cell pad)
    }
    if (d == N - 1) rp[(size_t)N * 8] = base + ((run + 3) & ~3);   // padded total
}

// ---------------- bucket: atomic-free scatter of PACKED gather index src*8+rel ----------------
__global__ __launch_bounds__(256) void bucket_kernel(const int* __restrict__ src,
                                                     const int* __restrict__ dst,
                                                     const int* __restrict__ et,
                                                     const int* __restrict__ rp,
                                                     const int* __restrict__ eoff,
                                                     int* __restrict__ srcs, int E) {
    int i = blockIdx.x * 256 + threadIdx.x;
    int half = (E + 1) >> 1;
    if (i >= half) return;
    int iB = i + half;
    bool hasB = iB < E;
    int etA = et[i];
    int etB = hasB ? et[iB] : 0;
    int cellA = dst[i] * 8 + etA;
    int cellB = hasB ? dst[iB] * 8 + etB : 0;
    int rA = rp[cellA];
    int rB = hasB ? rp[cellB] : 0;
    int oA = eoff[i];
    int oB = hasB ? eoff[iB] : 0;
    int sA = src[i];
    int sB = hasB ? src[iB] : 0;
    srcs[rA + oA] = sA * NREL + etA;                      // packed gidx
    if (hasB) srcs[rB + oB] = sB * NREL + etB;
}

// ---------------- layers (cooperative): [transform | aggroot] x L | score ----------------
// Replaces 5 dependent dispatches (2x transform, 2x aggroot, score) with ONE launch;
// phases separated by grid.sync(). All phases grid-strided so every CU works in every
// phase (R9 lesson: size the coop grid for the widest phase, not the narrowest).
__global__ __launch_bounds__(256) void layers_kernel(__bf16* __restrict__ xb0,
                                                     __bf16* __restrict__ xb1,
                                                     __bf16* __restrict__ hbuf,
                                                     const int* __restrict__ srcs,
                                                     const int* __restrict__ rp,
                                                     const float* __restrict__ invdeg,
                                                     const __bf16* __restrict__ Wt2,
                                                     const float* __restrict__ bias,
                                                     const int* __restrict__ ts,
                                                     const int* __restrict__ tt,
                                                     float* __restrict__ out,
                                                     int N, int T, int L) {
    cg::grid_group grid = cg::this_grid();
    __shared__ __align__(16) float S16[16][68];           // aggroot staging (pad 68)
    int wave = threadIdx.x >> 6;
    int lane = threadIdx.x & 63;
    int l15 = lane & 15;
    int lg  = lane >> 4;
    const int SENT = N * NREL;                            // sentinel gidx (zero row)
    int ntiles = (N + 15) >> 4;

    __bf16* xcur = xb0;
    __bf16* xnxt = xb1;
    for (int l = 0; l < L; ++l) {
        const __bf16* Wl = Wt2 + (size_t)l * KTOT * DIM;

        // ---------- phase T: transform (grid-stride; afrag hoisted once per phase) ----------
        {
            bf16x8 afrag[8][2];
#pragma unroll
            for (int p = 0; p < 8; ++p) {
                const __bf16* wrow = Wl + (size_t)(p * 64 + 16 * wave + l15) * DIM + lg * 8;
                afrag[p][0] = *reinterpret_cast<const bf16x8*>(wrow);
                afrag[p][1] = *reinterpret_cast<const bf16x8*>(wrow + 32);
            }
            int cb = 16 * wave + 4 * lg;
            for (int tile = blockIdx.x; tile < ntiles; tile += gridDim.x) {
                int n = tile * 16 + l15;
                int nc = (n < N) ? n : (N - 1);
                const __bf16* xrow = xcur + (size_t)nc * DIM + lg * 8;
                bf16x8 bv0 = *reinterpret_cast<const bf16x8*>(xrow);
                bf16x8 bv1 = *reinterpret_cast<const bf16x8*>(xrow + 32);
#pragma unroll
                for (int p = 0; p < 8; ++p) {
                    f32x4 acc = (f32x4){0.f, 0.f, 0.f, 0.f};
                    acc = __builtin_amdgcn_mfma_f32_16x16x32_bf16(afrag[p][0], bv0, acc, 0, 0, 0);
                    acc = __builtin_amdgcn_mfma_f32_16x16x32_bf16(afrag[p][1], bv1, acc, 0, 0, 0);
                    if (n < N) {
                        bf16x4 hv;
#pragma unroll
                        for (int i = 0; i < 4; ++i) hv[i] = (__bf16)acc[i];
                        *reinterpret_cast<bf16x4*>(hbuf + (size_t)n * (NREL * DIM) + p * 64 + cb) = hv;
                    }
                }
            }
        }
        grid.sync();

        // ---------- phase A: aggroot (grid-stride; 16-deep masked gathers + root GEMM) ----------
        {
            bf16x8 ar0, ar1;
            {
                const __bf16* wrow = Wl + (size_t)(512 + 16 * wave + l15) * DIM + lg * 8;
                ar0 = *reinterpret_cast<const bf16x8*>(wrow);
                ar1 = *reinterpret_cast<const bf16x8*>(wrow + 32);
            }
            int cbase = 16 * wave + 4 * lg;
            f32x4 bias4 = *reinterpret_cast<const f32x4*>(bias + (size_t)l * DIM + cbase);

            for (int tile = blockIdx.x; tile < ntiles; tile += gridDim.x) {
#pragma unroll
                for (int rr = 0; rr < 4; ++rr) {
                    int d0 = tile * 16 + wave * 4 + rr;
                    if (d0 >= N) d0 = N - 1;              // tail tile only
                    int d = __builtin_amdgcn_readfirstlane(d0);
                    int qb = rp[d * 8];
                    int qe = rp[d * 8 + 8];               // next row's base (= padded end)
                    float acc = 0.f;
                    for (int q = qb; q < qe; q += 16) {
                        int rem = qe - q;                 // multiple of 4, >= 4
                        int4 sa = *reinterpret_cast<const int4*>(srcs + q);
                        int4 sb = *reinterpret_cast<const int4*>(srcs + q + 4);
                        int4 sc = *reinterpret_cast<const int4*>(srcs + q + 8);
                        int4 sd = *reinterpret_cast<const int4*>(srcs + q + 12);
                        bool vb = rem >= 8, vc = rem >= 12, vd = rem >= 16;
                        int i0 = sa.x,             i1 = sa.y,             i2 = sa.z,             i3 = sa.w;
                        int i4 = vb ? sb.x : SENT, i5 = vb ? sb.y : SENT, i6 = vb ? sb.z : SENT, i7 = vb ? sb.w : SENT;
                        int i8 = vc ? sc.x : SENT, i9 = vc ? sc.y : SENT, iA = vc ? sc.z : SENT, iB = vc ? sc.w : SENT;
                        int iC = vd ? sd.x : SENT, iD = vd ? sd.y : SENT, iE = vd ? sd.z : SENT, iF = vd ? sd.w : SENT;
                        float v0 = (float)hbuf[(size_t)i0 * DIM + lane];
                        float v1 = (float)hbuf[(size_t)i1 * DIM + lane];
                        float v2 = (float)hbuf[(size_t)i2 * DIM + lane];
                        float v3 = (float)hbuf[(size_t)i3 * DIM + lane];
                        float v4 = (float)hbuf[(size_t)i4 * DIM + lane];
                        float v5 = (float)hbuf[(size_t)i5 * DIM + lane];
                        float v6 = (float)hbuf[(size_t)i6 * DIM + lane];
                        float v7 = (float)hbuf[(size_t)i7 * DIM + lane];
                        float v8 = (float)hbuf[(size_t)i8 * DIM + lane];
                        float v9 = (float)hbuf[(size_t)i9 * DIM + lane];
                        float vA = (float)hbuf[(size_t)iA * DIM + lane];
                        float vB = (float)hbuf[(size_t)iB * DIM + lane];
                        float vC = (float)hbuf[(size_t)iC * DIM + lane];
                        float vD = (float)hbuf[(size_t)iD * DIM + lane];
                        float vE = (float)hbuf[(size_t)iE * DIM + lane];
                        float vF = (float)hbuf[(size_t)iF * DIM + lane];
                        acc += (((v0 + v1) + (v2 + v3)) + ((v4 + v5) + (v6 + v7)))
                             + (((v8 + v9) + (vA + vB)) + ((vC + vD) + (vE + vF)));
                    }
                    S16[wave * 4 + rr][lane] = acc * invdeg[d];
                }
                __syncthreads();

                int n = tile * 16 + l15;
                int nc = (n < N) ? n : (N - 1);
                const __bf16* xrow = xcur + (size_t)nc * DIM + lg * 8;
                bf16x8 bv0 = *reinterpret_cast<const bf16x8*>(xrow);
                bf16x8 bv1 = *reinterpret_cast<const bf16x8*>(xrow + 32);
                f32x4 acc = (f32x4){0.f, 0.f, 0.f, 0.f};
                acc = __builtin_amdgcn_mfma_f32_16x16x32_bf16(ar0, bv0, acc, 0, 0, 0);
                acc = __builtin_amdgcn_mfma_f32_16x16x32_bf16(ar1, bv1, acc, 0, 0, 0);

                if (n < N) {
                    f32x4 ag = *reinterpret_cast<const f32x4*>(&S16[l15][cbase]);
                    bf16x4 hv;
#pragma unroll
                    for (int i = 0; i < 4; ++i)
                        hv[i] = (__bf16)fmaxf(acc[i] + ag[i] + bias4[i], 0.f);
                    *reinterpret_cast<bf16x4*>(xnxt + (size_t)n * DIM + cbase) = hv;
                }
                __syncthreads();                          // WAR: next tile rewrites S16
            }
        }
        grid.sync();

        __bf16* tmp = xcur; xcur = xnxt; xnxt = tmp;
    }

    // ---------- phase S: score (grid-stride, 1 wave per target) ----------
    for (int i = blockIdx.x * 4 + wave; i < T; i += gridDim.x * 4) {
        float p = (float)xcur[(size_t)ts[i] * DIM + lane] * (float)xcur[(size_t)tt[i] * DIM + lane];
#pragma unroll
        for (int off = 32; off > 0; off >>= 1) p += __shfl_down(p, off, 64);
        if (lane == 0) out[i] = p;
    }
}

extern "C" void kernel_launch(void* const* d_in, const int* in_sizes, int n_in,
                              void* d_out, int out_size, void* d_ws, size_t ws_size,
                              hipStream_t stream) {
    const int*   x_idx  = (const int*)d_in[0];
    const int*   eidx   = (const int*)d_in[1];   // [2,E]
    const int*   etyp   = (const int*)d_in[2];   // [E]
    const int*   tidx   = (const int*)d_in[3];   // [2,T]
    const float* emb    = (const float*)d_in[4]; // [N,64]
    const float* weight = (const float*)d_in[5]; // [L,8,64,64]
    const float* root   = (const float*)d_in[6]; // [L,64,64]
    const float* bias   = (const float*)d_in[7]; // [L,64]

    int N = in_sizes[0];
    int E = in_sizes[2];
    int T = in_sizes[3] / 2;
    int L = in_sizes[5] / (NREL * DIM * DIM);

    const int* src = eidx;
    const int* dst = eidx + E;
    const int* ts  = tidx;
    const int* tt  = tidx + T;
    float* out = (float*)d_out;

    int epad_cap = E + 3 * N + 64;              // per-row pad <= 3, + 16-deep over-read slack

    // ---- workspace carve-up ----
    char* p = (char*)d_ws;
    auto alloc = [&](size_t bytes) -> void* {
        void* r = (void*)p;
        p += (bytes + 255) & ~(size_t)255;
        return r;
    };
    __bf16* hbuf    = (__bf16*)alloc(((size_t)N * NREL + 1) * DIM * sizeof(__bf16)); // +1 zero row
    __bf16* xb0     = (__bf16*)alloc((size_t)N * DIM * sizeof(__bf16));
    __bf16* xb1     = (__bf16*)alloc((size_t)N * DIM * sizeof(__bf16));
    __bf16* Wt2     = (__bf16*)alloc((size_t)L * KTOT * DIM * sizeof(__bf16));
    int*    srcs    = (int*)   alloc((size_t)epad_cap * sizeof(int));
    int*    eoff    = (int*)   alloc((size_t)E * sizeof(int));
    int*    deg8    = (int*)   alloc((size_t)N * 8 * sizeof(int));
    int*    rp      = (int*)   alloc(((size_t)N * 8 + 1) * sizeof(int));
    int*    offs    = (int*)   alloc((size_t)N * sizeof(int));
    float*  invdeg  = (float*) alloc((size_t)N * sizeof(float));
    int*    bsum    = (int*)   alloc(1024 * sizeof(int));

    int nb = (N + 255) / 256;

    hipMemsetAsync(deg8, 0, (size_t)N * 8 * sizeof(int), stream);
    histgather_kernel<<<((size_t)N * DIM + 255) / 256, 256, 0, stream>>>(
        dst, etyp, deg8, eoff, x_idx, emb, xb0, hbuf, srcs, N, E, epad_cap);
    scan1_kernel<<<nb, 256, 0, stream>>>(deg8, offs, bsum, invdeg, N);
    {
        int wtotal = L * KTOT * DIM;
        int wblocks = 1 + (wtotal + 511) / 512;
        scan2wcat_kernel<<<wblocks, 512, 0, stream>>>(bsum, nb, weight, root, Wt2, L);
    }
    rpbuild_kernel<<<nb, 256, 0, stream>>>(deg8, offs, bsum, rp, N);
    {
        int half = (E + 1) / 2;
        bucket_kernel<<<(half + 255) / 256, 256, 0, stream>>>(src, dst, etyp, rp, eoff, srcs, E);
    }

    {   // cooperative layer loop + score: size grid by occupancy (R9 lesson), cap 1024
        int bpc = 0;
        hipOccupancyMaxActiveBlocksPerMultiprocessor(&bpc, (const void*)layers_kernel, 256, 0);
        if (bpc < 1) bpc = 1;
        int grid = bpc * 256;
        if (grid > 1024) grid = 1024;
        void* args[] = { (void*)&xb0, (void*)&xb1, (void*)&hbuf, (void*)&srcs,
                         (void*)&rp, (void*)&invdeg, (void*)&Wt2, (void*)&bias,
                         (void*)&ts, (void*)&tt, (void*)&out,
                         (void*)&N, (void*)&T, (void*)&L };
        hipLaunchCooperativeKernel((const void*)layers_kernel, dim3(grid), dim3(256),
                                   args, 0, stream);
    }
}

// Round 11
// 355.065 us; speedup vs baseline: 1.9966x; 1.9966x over previous
//
#include <hip/hip_runtime.h>
#include <hip/hip_bf16.h>

#define DIM 64
#define NREL 8
#define KTOT 576            // Wt2 rows: 512 rel-cols + 64 root cols

typedef __bf16 bf16x8 __attribute__((ext_vector_type(8)));
typedef __bf16 bf16x4 __attribute__((ext_vector_type(4)));
typedef float  f32x4  __attribute__((ext_vector_type(4)));

// ---------------- fused: hist (rank-returning) + initial gather + sentinels ----------------
__global__ __launch_bounds__(256) void histgather_kernel(const int* __restrict__ dst,
                                                         const int* __restrict__ et,
                                                         int* __restrict__ deg8,
                                                         int* __restrict__ eoff,
                                                         const int* __restrict__ x_idx,
                                                         const float* __restrict__ emb,
                                                         __bf16* __restrict__ xb0,
                                                         __bf16* __restrict__ hbuf,
                                                         int* __restrict__ srcs,
                                                         int N, int E, int epad_cap) {
    int i = blockIdx.x * 256 + threadIdx.x;
    if (i < N * DIM) {
        int n = i >> 6;
        int c = i & 63;
        xb0[i] = (__bf16)emb[(size_t)x_idx[n] * DIM + c];
    }
    if (i < DIM) {                                        // sentinel zero row in h (gidx = 8N)
        hbuf[(size_t)N * NREL * DIM + i] = (__bf16)0.f;
    }
    if (i < epad_cap) srcs[i] = N * NREL;                 // padding -> sentinel gidx
    if (i < E) eoff[i] = atomicAdd(&deg8[dst[i] * 8 + et[i]], 1);  // rank within (dst,rel) cell
}

// ---------------- scan1rp: scan1 + GLOBAL base via atomicAdd + rp/rend build + wcat ------
// Replaces scan1 -> scan2wcat -> rpbuild (3 dispatches) with ONE ordinary kernel.
// Block claims its slot-range with a single atomicAdd on gtotal (=deg8[N*8], memset to 0):
// placement is nondeterministic across blocks but each row gets a unique contiguous range,
// and per-row slot order is unchanged -> numerics identical up to existing atomic nondet.
// Row end goes to rend[] (next-row adjacency no longer holds). wcat folded as tail work.
__global__ __launch_bounds__(256) void scan1rp_kernel(const int* __restrict__ deg8,
                                                      int* __restrict__ gtotal,
                                                      float* __restrict__ invdeg,
                                                      int* __restrict__ rp,
                                                      int* __restrict__ rend,
                                                      const float* __restrict__ weight,
                                                      const float* __restrict__ root,
                                                      __bf16* __restrict__ Wt2,
                                                      int N, int L) {
    __shared__ int sd[256];
    __shared__ int sbase;
    int tid = threadIdx.x;
    int d = blockIdx.x * 256 + tid;
    int dv[NREL];
    int vpad = 0;
    if (d < N) {
        int vtrue = 0;
#pragma unroll
        for (int r = 0; r < NREL; ++r) { dv[r] = deg8[d * 8 + r]; vtrue += dv[r]; }
        vpad = (vtrue + 3) & ~3;                          // pad per ROW
        invdeg[d] = 1.0f / fmaxf((float)vtrue, 1.0f);
    }
    sd[tid] = vpad;
    __syncthreads();
#pragma unroll
    for (int off = 1; off < 256; off <<= 1) {             // inclusive block scan
        int t = (tid >= off) ? sd[tid - off] : 0;
        __syncthreads();
        sd[tid] += t;
        __syncthreads();
    }
    if (tid == 255) sbase = atomicAdd(gtotal, sd[255]);   // claim block's global range
    __syncthreads();
    if (d < N) {
        int base = sbase + sd[tid] - vpad;                // exclusive within block
        int run = 0;
#pragma unroll
        for (int r = 0; r < NREL; ++r) {
            rp[d * 8 + r] = base + run;
            run += dv[r];                                 // exact (no per-cell pad)
        }
        rend[d] = base + vpad;                            // padded row end
    }
    // ---- wcat tail: Wt2[l][row][ch]; row<512 -> weight[l][r][ch][c] (row=r*64+c);
    //                 row>=512 -> root[l][ch][row-512]
    int total = L * KTOT * DIM;
    for (int idx = blockIdx.x * 256 + tid; idx < total; idx += gridDim.x * 256) {
        int l = idx / (KTOT * DIM);
        int rem = idx - l * (KTOT * DIM);
        int row = rem / DIM;
        int ch = rem - row * DIM;
        float w;
        if (row < 512) {
            int r = row >> 6, c = row & 63;
            w = weight[(((l * 8 + r) * 64) + ch) * 64 + c];
        } else {
            w = root[(l * 64 + ch) * 64 + (row - 512)];
        }
        Wt2[idx] = (__bf16)w;
    }
}

// ---------------- bucket: atomic-free scatter of PACKED gather index src*8+rel ----------------
__global__ __launch_bounds__(256) void bucket_kernel(const int* __restrict__ src,
                                                     const int* __restrict__ dst,
                                                     const int* __restrict__ et,
                                                     const int* __restrict__ rp,
                                                     const int* __restrict__ eoff,
                                                     int* __restrict__ srcs, int E) {
    int i = blockIdx.x * 256 + threadIdx.x;
    int half = (E + 1) >> 1;
    if (i >= half) return;
    int iB = i + half;
    bool hasB = iB < E;
    int etA = et[i];
    int etB = hasB ? et[iB] : 0;
    int cellA = dst[i] * 8 + etA;
    int cellB = hasB ? dst[iB] * 8 + etB : 0;
    int rA = rp[cellA];
    int rB = hasB ? rp[cellB] : 0;
    int oA = eoff[i];
    int oB = hasB ? eoff[iB] : 0;
    int sA = src[i];
    int sB = hasB ? src[iB] : 0;
    srcs[rA + oA] = sA * NREL + etA;                      // packed gidx
    if (hasB) srcs[rB + oB] = sB * NREL + etB;
}

// ---------------- transform: grid-stride over 16-node tiles; afrag hoisted once ----------------
__global__ __launch_bounds__(256) void transform_kernel(const __bf16* __restrict__ xin,
                                                        const __bf16* __restrict__ Wt2,  // [576][64]
                                                        __bf16* __restrict__ h, int N) {
    int wave = threadIdx.x >> 6;
    int lane = threadIdx.x & 63;
    int l15 = lane & 15;
    int lg  = lane >> 4;

    bf16x8 afrag[8][2];
#pragma unroll
    for (int p = 0; p < 8; ++p) {
        const __bf16* wrow = Wt2 + (size_t)(p * 64 + 16 * wave + l15) * DIM + lg * 8;
        afrag[p][0] = *reinterpret_cast<const bf16x8*>(wrow);
        afrag[p][1] = *reinterpret_cast<const bf16x8*>(wrow + 32);
    }
    int cb = 16 * wave + 4 * lg;

    int ntiles = (N + 15) >> 4;
    for (int tile = blockIdx.x; tile < ntiles; tile += gridDim.x) {
        int n = tile * 16 + l15;
        int nc = (n < N) ? n : (N - 1);
        const __bf16* xrow = xin + (size_t)nc * DIM + lg * 8;
        bf16x8 bv0 = *reinterpret_cast<const bf16x8*>(xrow);
        bf16x8 bv1 = *reinterpret_cast<const bf16x8*>(xrow + 32);

#pragma unroll
        for (int p = 0; p < 8; ++p) {
            f32x4 acc = (f32x4){0.f, 0.f, 0.f, 0.f};
            acc = __builtin_amdgcn_mfma_f32_16x16x32_bf16(afrag[p][0], bv0, acc, 0, 0, 0);
            acc = __builtin_amdgcn_mfma_f32_16x16x32_bf16(afrag[p][1], bv1, acc, 0, 0, 0);
            if (n < N) {
                bf16x4 hv;
#pragma unroll
                for (int i = 0; i < 4; ++i) hv[i] = (__bf16)acc[i];
                *reinterpret_cast<bf16x4*>(h + (size_t)n * (NREL * DIM) + p * 64 + cb) = hv;
            }
        }
    }
}

// ---------------- aggroot: 16-deep masked gathers + root GEMM epilogue ----------------
__global__ __launch_bounds__(256) void aggroot_kernel(const __bf16* __restrict__ h,
                                                      const __bf16* __restrict__ xin,
                                                      const int* __restrict__ srcs,
                                                      const int* __restrict__ rp,
                                                      const int* __restrict__ rend,
                                                      const float* __restrict__ invdeg,
                                                      const __bf16* __restrict__ Wt2,   // rows 512..575
                                                      const float* __restrict__ bias_l, // [64]
                                                      __bf16* __restrict__ xout, int N) {
    __shared__ __align__(16) float S16[16][68];           // 68: pad -> conflict-free epilogue reads
    int wave = threadIdx.x >> 6;
    int lane = threadIdx.x & 63;
    int l15 = lane & 15;
    int lg  = lane >> 4;
    const int SENT = N * NREL;                            // sentinel gidx (zero row)

    bf16x8 ar0, ar1;
    {
        const __bf16* wrow = Wt2 + (size_t)(512 + 16 * wave + l15) * DIM + lg * 8;
        ar0 = *reinterpret_cast<const bf16x8*>(wrow);
        ar1 = *reinterpret_cast<const bf16x8*>(wrow + 32);
    }
    int cbase = 16 * wave + 4 * lg;
    f32x4 bias4 = *reinterpret_cast<const f32x4*>(bias_l + cbase);

    int tile = blockIdx.x;

    // ---------- phase A: 4 rows per wave, 16 gathers in flight ----------
#pragma unroll
    for (int rr = 0; rr < 4; ++rr) {
        int d0 = tile * 16 + wave * 4 + rr;
        if (d0 >= N) d0 = N - 1;                          // tail tile only
        int d = __builtin_amdgcn_readfirstlane(d0);
        int qb = rp[d * 8];
        int qe = rend[d];                                 // padded row end
        float acc = 0.f;
        for (int q = qb; q < qe; q += 16) {
            int rem = qe - q;                             // multiple of 4, >= 4
            int4 sa = *reinterpret_cast<const int4*>(srcs + q);
            int4 sb = *reinterpret_cast<const int4*>(srcs + q + 4);
            int4 sc = *reinterpret_cast<const int4*>(srcs + q + 8);
            int4 sd = *reinterpret_cast<const int4*>(srcs + q + 12);
            bool vb = rem >= 8, vc = rem >= 12, vd = rem >= 16;
            int i0 = sa.x,              i1 = sa.y,              i2 = sa.z,              i3 = sa.w;
            int i4 = vb ? sb.x : SENT,  i5 = vb ? sb.y : SENT,  i6 = vb ? sb.z : SENT,  i7 = vb ? sb.w : SENT;
            int i8 = vc ? sc.x : SENT,  i9 = vc ? sc.y : SENT,  iA = vc ? sc.z : SENT,  iB = vc ? sc.w : SENT;
            int iC = vd ? sd.x : SENT,  iD = vd ? sd.y : SENT,  iE = vd ? sd.z : SENT,  iF = vd ? sd.w : SENT;
            float v0 = (float)h[(size_t)i0 * DIM + lane];
            float v1 = (float)h[(size_t)i1 * DIM + lane];
            float v2 = (float)h[(size_t)i2 * DIM + lane];
            float v3 = (float)h[(size_t)i3 * DIM + lane];
            float v4 = (float)h[(size_t)i4 * DIM + lane];
            float v5 = (float)h[(size_t)i5 * DIM + lane];
            float v6 = (float)h[(size_t)i6 * DIM + lane];
            float v7 = (float)h[(size_t)i7 * DIM + lane];
            float v8 = (float)h[(size_t)i8 * DIM + lane];
            float v9 = (float)h[(size_t)i9 * DIM + lane];
            float vA = (float)h[(size_t)iA * DIM + lane];
            float vB = (float)h[(size_t)iB * DIM + lane];
            float vC = (float)h[(size_t)iC * DIM + lane];
            float vD = (float)h[(size_t)iD * DIM + lane];
            float vE = (float)h[(size_t)iE * DIM + lane];
            float vF = (float)h[(size_t)iF * DIM + lane];
            acc += (((v0 + v1) + (v2 + v3)) + ((v4 + v5) + (v6 + v7)))
                 + (((v8 + v9) + (vA + vB)) + ((vC + vD) + (vE + vF)));
        }
        S16[wave * 4 + rr][lane] = acc * invdeg[d];
    }
    __syncthreads();

    // ---------- phase B: root GEMM (K=64) + aggregate epilogue ----------
    int n = tile * 16 + l15;
    int nc = (n < N) ? n : (N - 1);
    const __bf16* xrow = xin + (size_t)nc * DIM + lg * 8;
    bf16x8 bv0 = *reinterpret_cast<const bf16x8*>(xrow);
    bf16x8 bv1 = *reinterpret_cast<const bf16x8*>(xrow + 32);
    f32x4 acc = (f32x4){0.f, 0.f, 0.f, 0.f};
    acc = __builtin_amdgcn_mfma_f32_16x16x32_bf16(ar0, bv0, acc, 0, 0, 0);
    acc = __builtin_amdgcn_mfma_f32_16x16x32_bf16(ar1, bv1, acc, 0, 0, 0);

    if (n < N) {
        f32x4 ag = *reinterpret_cast<const f32x4*>(&S16[l15][cbase]);
        bf16x4 hv;
#pragma unroll
        for (int i = 0; i < 4; ++i)
            hv[i] = (__bf16)fmaxf(acc[i] + ag[i] + bias4[i], 0.f);
        *reinterpret_cast<bf16x4*>(xout + (size_t)n * DIM + cbase) = hv;
    }
}

// ---------------- score ----------------
__global__ __launch_bounds__(256) void score_kernel(const __bf16* __restrict__ xb,
                                                    const int* __restrict__ s,
                                                    const int* __restrict__ t,
                                                    float* __restrict__ out, int T) {
    int i = blockIdx.x * 4 + (threadIdx.x >> 6);
    if (i >= T) return;
    int lane = threadIdx.x & 63;
    float p = (float)xb[(size_t)s[i] * DIM + lane] * (float)xb[(size_t)t[i] * DIM + lane];
#pragma unroll
    for (int off = 32; off > 0; off >>= 1) p += __shfl_down(p, off, 64);
    if (lane == 0) out[i] = p;
}

extern "C" void kernel_launch(void* const* d_in, const int* in_sizes, int n_in,
                              void* d_out, int out_size, void* d_ws, size_t ws_size,
                              hipStream_t stream) {
    const int*   x_idx  = (const int*)d_in[0];
    const int*   eidx   = (const int*)d_in[1];   // [2,E]
    const int*   etyp   = (const int*)d_in[2];   // [E]
    const int*   tidx   = (const int*)d_in[3];   // [2,T]
    const float* emb    = (const float*)d_in[4]; // [N,64]
    const float* weight = (const float*)d_in[5]; // [L,8,64,64]
    const float* root   = (const float*)d_in[6]; // [L,64,64]
    const float* bias   = (const float*)d_in[7]; // [L,64]

    int N = in_sizes[0];
    int E = in_sizes[2];
    int T = in_sizes[3] / 2;
    int L = in_sizes[5] / (NREL * DIM * DIM);

    const int* src = eidx;
    const int* dst = eidx + E;
    const int* ts  = tidx;
    const int* tt  = tidx + T;
    float* out = (float*)d_out;

    int epad_cap = E + 3 * N + 64;              // per-row pad <= 3, + 16-deep over-read slack

    // ---- workspace carve-up ----
    char* p = (char*)d_ws;
    auto alloc = [&](size_t bytes) -> void* {
        void* r = (void*)p;
        p += (bytes + 255) & ~(size_t)255;
        return r;
    };
    __bf16* hbuf    = (__bf16*)alloc(((size_t)N * NREL + 1) * DIM * sizeof(__bf16)); // +1 zero row
    __bf16* xb0     = (__bf16*)alloc((size_t)N * DIM * sizeof(__bf16));
    __bf16* xb1     = (__bf16*)alloc((size_t)N * DIM * sizeof(__bf16));
    __bf16* Wt2     = (__bf16*)alloc((size_t)L * KTOT * DIM * sizeof(__bf16));
    int*    srcs    = (int*)   alloc((size_t)epad_cap * sizeof(int));
    int*    eoff    = (int*)   alloc((size_t)E * sizeof(int));
    int*    deg8    = (int*)   alloc(((size_t)N * 8 + 8) * sizeof(int));  // +8: gtotal at [N*8]
    int*    rp      = (int*)   alloc((size_t)N * 8 * sizeof(int));
    int*    rend    = (int*)   alloc((size_t)N * sizeof(int));
    float*  invdeg  = (float*) alloc((size_t)N * sizeof(float));

    int* gtotal = deg8 + (size_t)N * 8;         // zeroed by the same memset

    int nb = (N + 255) / 256;
    int ntiles = (N + 15) / 16;

    hipMemsetAsync(deg8, 0, ((size_t)N * 8 + 8) * sizeof(int), stream);
    histgather_kernel<<<((size_t)N * DIM + 255) / 256, 256, 0, stream>>>(
        dst, etyp, deg8, eoff, x_idx, emb, xb0, hbuf, srcs, N, E, epad_cap);
    scan1rp_kernel<<<nb, 256, 0, stream>>>(deg8, gtotal, invdeg, rp, rend,
                                           weight, root, Wt2, N, L);
    {
        int half = (E + 1) / 2;
        bucket_kernel<<<(half + 255) / 256, 256, 0, stream>>>(src, dst, etyp, rp, eoff, srcs, E);
    }

    __bf16* xcur = xb0;
    __bf16* xnxt = xb1;
    for (int l = 0; l < L; ++l) {
        transform_kernel<<<2048, 256, 0, stream>>>(xcur, Wt2 + (size_t)l * KTOT * DIM, hbuf, N);
        aggroot_kernel<<<ntiles, 256, 0, stream>>>(hbuf, xcur, srcs, rp, rend, invdeg,
                                                   Wt2 + (size_t)l * KTOT * DIM,
                                                   bias + (size_t)l * DIM,
                                                   xnxt, N);
        __bf16* tmp = xcur; xcur = xnxt; xnxt = tmp;
    }

    score_kernel<<<(T + 3) / 4, 256, 0, stream>>>(xcur, ts, tt, out, T);
}